// Round 3
// baseline (230.400 us; speedup 1.0000x reference)
//
#include <hip/hip_runtime.h>
#include <cstdint>
#include <cstddef>

typedef _Float16 h16;
typedef __attribute__((ext_vector_type(8))) _Float16 half8;
typedef __attribute__((ext_vector_type(2))) _Float16 half2v;
typedef __attribute__((ext_vector_type(4))) float f32x4;
typedef __attribute__((ext_vector_type(2))) float f32x2;

#define NB 16384
#define NTAB 26
#define NR 100000

__device__ __forceinline__ void gload16(const void* g, void* l) {
  __builtin_amdgcn_global_load_lds(
      (const __attribute__((address_space(1))) unsigned int*)g,
      (__attribute__((address_space(3))) unsigned int*)l, 16, 0, 0);
}

template <int N>
__device__ __forceinline__ void waitvN() {
  if constexpr (N == 8)
    asm volatile("s_waitcnt vmcnt(8)" ::: "memory");
  else
    asm volatile("s_waitcnt vmcnt(6)" ::: "memory");
}

// ---- bottom layer 0: Y[B,512] = relu(x[B,13] @ W0[512,13]^T + b0), fp16 out
__global__ __launch_bounds__(256) void bot0_k(
    const float* __restrict__ x, const float* __restrict__ W,
    const float* __restrict__ bias, h16* __restrict__ Y) {
  int gid = blockIdx.x * 256 + threadIdx.x;
  int row = gid >> 9;
  int n = gid & 511;
  const float* xr = x + row * 13;
  const float* wr = W + n * 13;
  float acc = bias[n];
#pragma unroll
  for (int k = 0; k < 13; ++k) acc += xr[k] * wr[k];
  Y[gid] = (h16)fmaxf(acc, 0.f);
}

// ---- fused f32 -> fp16 weight conversion (all 6 weights, one launch)
__global__ __launch_bounds__(256) void cvt_all_k(
    const float* __restrict__ s0, const float* __restrict__ s1,
    const float* __restrict__ s2, const float* __restrict__ s3,
    const float* __restrict__ s4, const float* __restrict__ s5,
    h16* __restrict__ dst) {
  int b = blockIdx.x;
  const float* src; int K, Kp, i0; size_t doff;
  if (b < 512)       { src=s0; K=512;  Kp=512;  i0=(b-0)*256;    doff=0; }
  else if (b < 640)  { src=s1; K=256;  Kp=256;  i0=(b-512)*256;  doff=131072; }
  else if (b < 2688) { src=s2; K=479;  Kp=512;  i0=(b-640)*256;  doff=163840; }
  else if (b < 6784) { src=s3; K=1024; Kp=1024; i0=(b-2688)*256; doff=688128; }
  else if (b < 8832) { src=s4; K=1024; Kp=1024; i0=(b-6784)*256; doff=1736704; }
  else               { src=s5; K=512;  Kp=512;  i0=(b-8832)*256; doff=2260992; }
  int i = i0 + threadIdx.x;
  int n = i / Kp, k = i - n * Kp;
  dst[doff + i] = (k < K) ? (h16)src[(size_t)n * K + k] : (h16)0.f;
}

// ---- 128x128-tile fp16 MFMA GEMM (small-N layers):
__global__ __launch_bounds__(256, 2) void gemm_h(
    const h16* __restrict__ A, const h16* __restrict__ W,
    const float* __restrict__ bias, h16* __restrict__ C, int N, int K) {
  __shared__ __align__(16) h16 As[128 * 64];
  __shared__ __align__(16) h16 Bs[128 * 64];
  const int tid = threadIdx.x;
  const int lane = tid & 63;
  const int wave = tid >> 6;
  const int wm = wave >> 1, wn = wave & 1;
  const size_t row0 = (size_t)blockIdx.x * 128;
  const size_t col0 = (size_t)blockIdx.y * 128;
  const int lr = lane >> 3;
  const int swzc = (((lane & 7) ^ lr) << 3);
  const int l15 = lane & 15;
  const int kq = lane >> 4;
  const int l7 = lane & 7;

  f32x4 acc[4][4] = {};

  for (int k0 = 0; k0 < K; k0 += 64) {
    __syncthreads();
    const h16* ga = A + (row0 + wave * 32 + lr) * (size_t)K + k0 + swzc;
    const h16* gb = W + (col0 + wave * 32 + lr) * (size_t)K + k0 + swzc;
    h16* la = As + wave * 32 * 64;
    h16* lb = Bs + wave * 32 * 64;
#pragma unroll
    for (int i = 0; i < 4; ++i) {
      gload16(ga + (size_t)i * 8 * K, la + i * 8 * 64);
      gload16(gb + (size_t)i * 8 * K, lb + i * 8 * 64);
    }
    asm volatile("s_waitcnt vmcnt(0)" ::: "memory");
    __syncthreads();
#pragma unroll
    for (int kk = 0; kk < 2; ++kk) {
      half8 a[4], b[4];
      const int kb = kk * 4 + kq;
#pragma unroll
      for (int mi = 0; mi < 4; ++mi)
        a[mi] = *(const half8*)&As[(wm * 64 + mi * 16 + l15) * 64 + ((kb ^ l7) << 3)];
#pragma unroll
      for (int ni = 0; ni < 4; ++ni)
        b[ni] = *(const half8*)&Bs[(wn * 64 + ni * 16 + l15) * 64 + ((kb ^ l7) << 3)];
#pragma unroll
      for (int mi = 0; mi < 4; ++mi)
#pragma unroll
        for (int ni = 0; ni < 4; ++ni)
          acc[mi][ni] = __builtin_amdgcn_mfma_f32_16x16x32_f16(a[mi], b[ni], acc[mi][ni], 0, 0, 0);
    }
  }

#pragma unroll
  for (int mi = 0; mi < 4; ++mi)
#pragma unroll
    for (int ni = 0; ni < 4; ++ni) {
      const size_t col = col0 + wn * 64 + ni * 16 + l15;
      const float bv = bias[col];
#pragma unroll
      for (int ri = 0; ri < 4; ++ri) {
        const size_t row = row0 + wm * 64 + mi * 16 + kq * 4 + ri;
        float v = acc[mi][ni][ri] + bv;
        C[row * N + col] = (h16)fmaxf(v, 0.f);
      }
    }
}

// ---- 8-phase-style pipelined fp16 MFMA GEMM (BM x 256 tile, BK=64).
// 512 threads, 8 waves (2m x 4n). Per wave: (BM/2) x 64 output, MR=BM/32
// m-frags. LDS split per (dbuf, k-half) sub-buffer; counted vmcnt (never 0
// in loop); staging runs 1.5-2 K-tiles ahead with index wrap; setprio
// around each 16/8-MFMA cluster; XOR chunk swizzle (inverse-swizzled
// global source, linear global_load_lds dest).
template <int BM>
__global__ __launch_bounds__(512, 2) void gemm8p(
    const h16* __restrict__ A, const h16* __restrict__ W,
    const float* __restrict__ bias, h16* __restrict__ C, int N, int K) {
  constexpr int MR = BM / 32;    // m-frags per wave
  constexpr int MR_H = MR / 2;   // m-frags per phase
  constexpr int AGL = BM / 128;  // A gloads per (ks-half, thread)
  constexpr int WAIT = 2 * AGL + 4;
  __shared__ __align__(16) h16 As[2][2][BM * 32];
  __shared__ __align__(16) h16 Bs[2][2][256 * 32];
  const int tid = threadIdx.x;
  const int lane = tid & 63;
  const int wave = tid >> 6;
  const int wm = wave >> 2;  // 0..1
  const int wn = wave & 3;   // 0..3
  const size_t row0 = (size_t)blockIdx.x * BM;
  const size_t col0 = (size_t)blockIdx.y * 256;
  const int l15 = lane & 15;
  const int kq = lane >> 4;
  const int srow = tid >> 2;                        // 0..127
  const int scg = (tid & 3) ^ ((tid >> 3) & 3);     // inverse-swizzled chunk
  const int nt = K >> 6;

  const h16* pA = A + (row0 + srow) * (size_t)K + scg * 8;
  const h16* pB = W + (col0 + srow) * (size_t)K + scg * 8;

  f32x4 acc[MR][4] = {};

  auto stA = [&](int buf, int ks, int kt) {
    if (kt >= nt) kt -= nt;
    const int off = kt * 64 + ks * 32;
#pragma unroll
    for (int i = 0; i < AGL; ++i)
      gload16(pA + (size_t)(i * 128) * K + off, &As[buf][ks][i * 4096 + tid * 8]);
  };
  auto stB = [&](int buf, int ks, int kt) {
    if (kt >= nt) kt -= nt;
    const int off = kt * 64 + ks * 32;
#pragma unroll
    for (int i = 0; i < 2; ++i)
      gload16(pB + (size_t)(i * 128) * K + off, &Bs[buf][ks][i * 4096 + tid * 8]);
  };

#define PHASE(p, ks, mh, STAGE, DOWAIT)                                        \
  do {                                                                         \
    if ((mh) == 0) {                                                           \
      _Pragma("unroll") for (int ni = 0; ni < 4; ++ni) {                       \
        int r = wn * 64 + ni * 16 + l15;                                       \
        int slot = kq ^ ((r >> 1) & 3);                                        \
        b[ni] = *(const half8*)&Bs[p][ks][r * 32 + slot * 8];                  \
      }                                                                        \
    }                                                                          \
    half8 a[MR_H];                                                             \
    _Pragma("unroll") for (int i = 0; i < MR_H; ++i) {                         \
      int r = wm * (MR * 16) + ((mh) * MR_H + i) * 16 + l15;                   \
      int slot = kq ^ ((r >> 1) & 3);                                          \
      a[i] = *(const half8*)&As[p][ks][r * 32 + slot * 8];                     \
    }                                                                          \
    STAGE;                                                                     \
    if (DOWAIT) waitvN<WAIT>();                                                \
    __builtin_amdgcn_s_barrier();                                              \
    __builtin_amdgcn_sched_barrier(0);                                         \
    asm volatile("s_waitcnt lgkmcnt(0)" ::: "memory");                         \
    __builtin_amdgcn_sched_barrier(0);                                         \
    __builtin_amdgcn_s_setprio(1);                                             \
    _Pragma("unroll") for (int i = 0; i < MR_H; ++i)                           \
        _Pragma("unroll") for (int ni = 0; ni < 4; ++ni)                       \
            acc[(mh) * MR_H + i][ni] = __builtin_amdgcn_mfma_f32_16x16x32_f16( \
                a[i], b[ni], acc[(mh) * MR_H + i][ni], 0, 0, 0);               \
    __builtin_amdgcn_s_setprio(0);                                             \
    __builtin_amdgcn_s_barrier();                                              \
    __builtin_amdgcn_sched_barrier(0);                                         \
  } while (0)

  // prologue: SG(0,ks0), SG(0,ks1), SG(1,ks0); wait so SG(0,ks0) landed
  stA(0, 0, 0); stB(0, 0, 0);
  stA(0, 1, 0); stB(0, 1, 0);
  stA(1, 0, 1); stB(1, 0, 1);
  waitvN<WAIT>();
  __builtin_amdgcn_s_barrier();
  __builtin_amdgcn_sched_barrier(0);

  for (int t = 0; t < nt; ++t) {
    const int p = t & 1;
    half8 b[4];
    PHASE(p, 0, 0, stA(p ^ 1, 1, t + 1), false);
    PHASE(p, 0, 1, stB(p ^ 1, 1, t + 1), true);
    PHASE(p, 1, 0, stA(p, 0, t + 2), false);
    PHASE(p, 1, 1, stB(p, 0, t + 2), true);
  }
#undef PHASE

#pragma unroll
  for (int mi = 0; mi < MR; ++mi)
#pragma unroll
    for (int ni = 0; ni < 4; ++ni) {
      const size_t col = col0 + wn * 64 + ni * 16 + l15;
      const float bv = bias[col];
#pragma unroll
      for (int ri = 0; ri < 4; ++ri) {
        const size_t row = row0 + wm * (MR * 16) + mi * 16 + kq * 4 + ri;
        float v = acc[mi][ni][ri] + bv;
        C[row * N + col] = (h16)fmaxf(v, 0.f);
      }
    }
}

// ---- fused embedding gather + interaction.
__global__ __launch_bounds__(256) void interact_k(
    const h16* __restrict__ X, const float* __restrict__ emb,
    const int* __restrict__ lSi, h16* __restrict__ z) {
  __shared__ __align__(16) h16 T[4][32][136];
  const int lane = threadIdx.x & 63;
  const int wv = threadIdx.x >> 6;
  const size_t b = (size_t)blockIdx.x * 4 + wv;

  for (int i = lane; i < 5 * 128; i += 64)
    T[wv][27 + (i >> 7)][i & 127] = (h16)0.f;

  {
    half2v v = *(const half2v*)(X + b * 128 + lane * 2);
    *(half2v*)&T[wv][0][lane * 2] = v;
    *(half2v*)(z + b * 512 + lane * 2) = v;
  }
  for (int t = 0; t < NTAB; ++t) {
    int idx = lSi[t * NB + (int)b];
    f32x2 v = *(const f32x2*)(emb + ((size_t)t * NR + idx) * 128 + lane * 2);
    half2v h;
    h[0] = (h16)v.x;
    h[1] = (h16)v.y;
    *(half2v*)&T[wv][1 + t][lane * 2] = h;
  }

  __syncthreads();

  f32x4 acc00 = {}, acc10 = {}, acc11 = {};
  const int l15 = lane & 15;
  const int kq = lane >> 4;
#pragma unroll
  for (int kk = 0; kk < 4; ++kk) {
    const int ko = kk * 32 + kq * 8;
    half8 a0 = *(const half8*)&T[wv][l15][ko];
    half8 a1 = *(const half8*)&T[wv][16 + l15][ko];
    acc00 = __builtin_amdgcn_mfma_f32_16x16x32_f16(a0, a0, acc00, 0, 0, 0);
    acc10 = __builtin_amdgcn_mfma_f32_16x16x32_f16(a1, a0, acc10, 0, 0, 0);
    acc11 = __builtin_amdgcn_mfma_f32_16x16x32_f16(a1, a1, acc11, 0, 0, 0);
  }
  h16* zr = z + b * 512 + 128;
#pragma unroll
  for (int ri = 0; ri < 4; ++ri) {
    int i0 = kq * 4 + ri;
    int i1 = 16 + i0;
    if (l15 < i0) zr[i0 * (i0 - 1) / 2 + l15] = (h16)acc00[ri];
    if (i1 < 27) {
      zr[i1 * (i1 - 1) / 2 + l15] = (h16)acc10[ri];
      int j1 = 16 + l15;
      if (j1 < i1) zr[i1 * (i1 - 1) / 2 + j1] = (h16)acc11[ri];
    }
  }
}

// ---- final layer: out[b] = sigmoid(U3[b,:256] . tw4 + tb4), f32 out
__global__ __launch_bounds__(256) void top4_k(
    const h16* __restrict__ U, const float* __restrict__ w,
    const float* __restrict__ bias, float* __restrict__ out) {
  int r = blockIdx.x * 256 + threadIdx.x;
  const h16* ur = U + (size_t)r * 256;
  float acc = 0.f;
#pragma unroll
  for (int k0 = 0; k0 < 256; k0 += 8) {
    half8 v = *(const half8*)&ur[k0];
#pragma unroll
    for (int j = 0; j < 8; ++j) acc += (float)v[j] * w[k0 + j];
  }
  acc += bias[0];
  out[r] = 1.f / (1.f + expf(-acc));
}

extern "C" void kernel_launch(void* const* d_in, const int* in_sizes, int n_in,
                              void* d_out, int out_size, void* d_ws, size_t ws_size,
                              hipStream_t stream) {
  const float* dense_x = (const float*)d_in[0];
  const int* lSi = (const int*)d_in[2];
  const float* emb = (const float*)d_in[3];
  const float* bw0 = (const float*)d_in[4];
  const float* bb0 = (const float*)d_in[5];
  const float* bw1 = (const float*)d_in[6];
  const float* bb1 = (const float*)d_in[7];
  const float* bw2 = (const float*)d_in[8];
  const float* bb2 = (const float*)d_in[9];
  const float* tw0 = (const float*)d_in[10];
  const float* tb0 = (const float*)d_in[11];
  const float* tw1 = (const float*)d_in[12];
  const float* tb1 = (const float*)d_in[13];
  const float* tw2 = (const float*)d_in[14];
  const float* tb2 = (const float*)d_in[15];
  const float* tw3 = (const float*)d_in[16];
  const float* tb3 = (const float*)d_in[17];
  const float* tw4 = (const float*)d_in[18];
  const float* tb4 = (const float*)d_in[19];
  float* out = (float*)d_out;

  char* ws = (char*)d_ws;
  const size_t MB = (size_t)1 << 20;
  h16* Y0 = (h16*)(ws + 0 * MB);    // [B,512]   16MB   (dead after L1)
  h16* Y1 = (h16*)(ws + 16 * MB);   // [B,256]    8MB   (dead after L2)
  h16* Xc = (h16*)(ws + 24 * MB);   // [B,128]    4MB   (dead after interact)
  h16* Zz = (h16*)(ws + 32 * MB);   // [B,512]   16MB   (dead after T0)
  h16* U0 = (h16*)(ws + 48 * MB);   // [B,1024]  32MB   (dead after T1)
  h16* U1 = (h16*)(ws + 0 * MB);    // [B,1024]  32MB   reuses Y0/Y1/Xc
  h16* U2 = (h16*)(ws + 32 * MB);   // [B,512]   16MB   reuses Zz
  h16* U3 = (h16*)(ws + 48 * MB);   // [B,256]    8MB   reuses U0
  h16* w1p = (h16*)(ws + 80 * MB);  // fp16 weights, contiguous segments
  h16* w2p = w1p + 256 * 512;
  h16* t0p = w2p + 128 * 256;
  h16* t1p = t0p + 1024 * 512;
  h16* t2p = t1p + 1024 * 1024;
  h16* t3p = t2p + 512 * 1024;
  (void)in_sizes; (void)n_in; (void)out_size; (void)ws_size;

  cvt_all_k<<<9344, 256, 0, stream>>>(bw1, bw2, tw0, tw1, tw2, tw3, w1p);

  bot0_k<<<NB * 512 / 256, 256, 0, stream>>>(dense_x, bw0, bb0, Y0);
  gemm_h<<<dim3(NB / 128, 2), 256, 0, stream>>>(Y0, w1p, bb1, Y1, 256, 512);
  gemm_h<<<dim3(NB / 128, 1), 256, 0, stream>>>(Y1, w2p, bb2, Xc, 128, 256);
  interact_k<<<NB / 4, 256, 0, stream>>>(Xc, emb, lSi, Zz);
  gemm8p<256><<<dim3(NB / 256, 4), 512, 0, stream>>>(Zz, t0p, tb0, U0, 1024, 512);
  gemm8p<256><<<dim3(NB / 256, 4), 512, 0, stream>>>(U0, t1p, tb1, U1, 1024, 1024);
  gemm8p<128><<<dim3(NB / 128, 2), 512, 0, stream>>>(U1, t2p, tb2, U2, 512, 1024);
  gemm_h<<<dim3(NB / 128, 2), 256, 0, stream>>>(U2, t3p, tb3, U3, 256, 512);
  top4_k<<<NB / 256, 256, 0, stream>>>(U3, tw4, tb4, out);
}

// Round 4
// 222.835 us; speedup vs baseline: 1.0339x; 1.0339x over previous
//
#include <hip/hip_runtime.h>
#include <cstdint>
#include <cstddef>

typedef _Float16 h16;
typedef __attribute__((ext_vector_type(8))) _Float16 half8;
typedef __attribute__((ext_vector_type(2))) _Float16 half2v;
typedef __attribute__((ext_vector_type(4))) float f32x4;
typedef __attribute__((ext_vector_type(2))) float f32x2;

#define NB 16384
#define NTAB 26
#define NR 100000

__device__ __forceinline__ void gload16(const void* g, void* l) {
  __builtin_amdgcn_global_load_lds(
      (const __attribute__((address_space(1))) unsigned int*)g,
      (__attribute__((address_space(3))) unsigned int*)l, 16, 0, 0);
}

template <int N>
__device__ __forceinline__ void waitvN() {
  if constexpr (N == 8)
    asm volatile("s_waitcnt vmcnt(8)" ::: "memory");
  else
    asm volatile("s_waitcnt vmcnt(6)" ::: "memory");
}

// ---- bottom layer 0: Y[B,512] = relu(x[B,13] @ W0[512,13]^T + b0), fp16 out
__global__ __launch_bounds__(256) void bot0_k(
    const float* __restrict__ x, const float* __restrict__ W,
    const float* __restrict__ bias, h16* __restrict__ Y) {
  int gid = blockIdx.x * 256 + threadIdx.x;
  int row = gid >> 9;
  int n = gid & 511;
  const float* xr = x + row * 13;
  const float* wr = W + n * 13;
  float acc = bias[n];
#pragma unroll
  for (int k = 0; k < 13; ++k) acc += xr[k] * wr[k];
  Y[gid] = (h16)fmaxf(acc, 0.f);
}

// ---- fused f32 -> fp16 weight conversion (all 6 weights, one launch)
__global__ __launch_bounds__(256) void cvt_all_k(
    const float* __restrict__ s0, const float* __restrict__ s1,
    const float* __restrict__ s2, const float* __restrict__ s3,
    const float* __restrict__ s4, const float* __restrict__ s5,
    h16* __restrict__ dst) {
  int b = blockIdx.x;
  const float* src; int K, Kp, i0; size_t doff;
  if (b < 512)       { src=s0; K=512;  Kp=512;  i0=(b-0)*256;    doff=0; }
  else if (b < 640)  { src=s1; K=256;  Kp=256;  i0=(b-512)*256;  doff=131072; }
  else if (b < 2688) { src=s2; K=479;  Kp=512;  i0=(b-640)*256;  doff=163840; }
  else if (b < 6784) { src=s3; K=1024; Kp=1024; i0=(b-2688)*256; doff=688128; }
  else if (b < 8832) { src=s4; K=1024; Kp=1024; i0=(b-6784)*256; doff=1736704; }
  else               { src=s5; K=512;  Kp=512;  i0=(b-8832)*256; doff=2260992; }
  int i = i0 + threadIdx.x;
  int n = i / Kp, k = i - n * Kp;
  dst[doff + i] = (k < K) ? (h16)src[(size_t)n * K + k] : (h16)0.f;
}

// ---- 128x128-tile double-buffered counted-vmcnt fp16 MFMA GEMM (small-N):
// C[M,N] = relu(A[M,K] @ W[N,K]^T + bias). 4 waves (2x2 of 64x64), BK=64.
// Loop never drains vmcnt; 2 raw barriers per K-tile; wrap-prefetch keeps
// vmcnt arithmetic uniform (8 loads/thread/tile -> wait vmcnt(8)).
__global__ __launch_bounds__(256, 2) void gemm_hd(
    const h16* __restrict__ A, const h16* __restrict__ W,
    const float* __restrict__ bias, h16* __restrict__ C, int N, int K) {
  __shared__ __align__(16) h16 As[2][128 * 64];
  __shared__ __align__(16) h16 Bs[2][128 * 64];
  const int tid = threadIdx.x;
  const int lane = tid & 63;
  const int wave = tid >> 6;
  const int wm = wave >> 1, wn = wave & 1;
  const size_t row0 = (size_t)blockIdx.x * 128;
  const size_t col0 = (size_t)blockIdx.y * 128;
  const int lr = lane >> 3;
  const int swzc = (((lane & 7) ^ lr) << 3);
  const int l15 = lane & 15;
  const int kq = lane >> 4;
  const int l7 = lane & 7;
  const int nt = K >> 6;

  const h16* ga = A + (row0 + wave * 32 + lr) * (size_t)K + swzc;
  const h16* gb = W + (col0 + wave * 32 + lr) * (size_t)K + swzc;

  f32x4 acc[4][4] = {};

  auto stage = [&](int buf, int kt) {
    if (kt >= nt) kt -= nt;
    const int k0 = kt << 6;
    h16* la = As[buf] + wave * 2048;
    h16* lb = Bs[buf] + wave * 2048;
#pragma unroll
    for (int i = 0; i < 4; ++i) {
      gload16(ga + (size_t)i * 8 * K + k0, la + i * 512);
      gload16(gb + (size_t)i * 8 * K + k0, lb + i * 512);
    }
  };

  stage(0, 0);
  for (int t = 0; t < nt; ++t) {
    const int p = t & 1;
    stage(p ^ 1, t + 1);
    waitvN<8>();
    __builtin_amdgcn_s_barrier();
    __builtin_amdgcn_sched_barrier(0);
#pragma unroll
    for (int kk = 0; kk < 2; ++kk) {
      half8 a[4], b[4];
      const int kb = kk * 4 + kq;
#pragma unroll
      for (int mi = 0; mi < 4; ++mi)
        a[mi] = *(const half8*)&As[p][(wm * 64 + mi * 16 + l15) * 64 + ((kb ^ l7) << 3)];
#pragma unroll
      for (int ni = 0; ni < 4; ++ni)
        b[ni] = *(const half8*)&Bs[p][(wn * 64 + ni * 16 + l15) * 64 + ((kb ^ l7) << 3)];
#pragma unroll
      for (int mi = 0; mi < 4; ++mi)
#pragma unroll
        for (int ni = 0; ni < 4; ++ni)
          acc[mi][ni] = __builtin_amdgcn_mfma_f32_16x16x32_f16(a[mi], b[ni], acc[mi][ni], 0, 0, 0);
    }
    __builtin_amdgcn_sched_barrier(0);
    __builtin_amdgcn_s_barrier();
    __builtin_amdgcn_sched_barrier(0);
  }

#pragma unroll
  for (int mi = 0; mi < 4; ++mi)
#pragma unroll
    for (int ni = 0; ni < 4; ++ni) {
      const size_t col = col0 + wn * 64 + ni * 16 + l15;
      const float bv = bias[col];
#pragma unroll
      for (int ri = 0; ri < 4; ++ri) {
        const size_t row = row0 + wm * 64 + mi * 16 + kq * 4 + ri;
        float v = acc[mi][ni][ri] + bv;
        C[row * N + col] = (h16)fmaxf(v, 0.f);
      }
    }
}

// ---- 256-row-tile counted-vmcnt fp16 MFMA GEMM for the big top-MLP layers.
// BM=256, BK=64, 8 waves, 512 threads. BN=256: wave grid 2x4 (per-wave
// 128x64); BN=128: 4x2 (per-wave 64x64). Double-buffered LDS, XOR chunk
// swizzle (inverse-swizzled global source, linear global_load_lds dest).
// Loop never drains vmcnt: wait vmcnt(NLD) leaves next tile's loads in
// flight across both raw barriers.
template <int BN>
__global__ __launch_bounds__(512, 2) void gemm256(
    const h16* __restrict__ A, const h16* __restrict__ W,
    const float* __restrict__ bias, h16* __restrict__ C, int N, int K) {
  constexpr int WN = (BN == 256) ? 4 : 2;
  constexpr int MR = (BN == 256) ? 8 : 4;
  constexpr int NLD = 4 + BN / 64;  // per-thread gloads per K-tile
  __shared__ __align__(16) h16 As[2][256 * 64];
  __shared__ __align__(16) h16 Bs[2][BN * 64];
  const int tid = threadIdx.x;
  const int lane = tid & 63;
  const int wave = tid >> 6;
  const int wm = wave / WN, wn = wave % WN;
  const size_t row0 = (size_t)blockIdx.x * 256;
  const size_t col0 = (size_t)blockIdx.y * BN;
  const int l15 = lane & 15;
  const int kq = lane >> 4;
  const int srow = tid >> 3;                     // 0..63
  const int sschunk = (tid & 7) ^ (srow & 7);    // inverse-swizzled chunk
  const int nt = K >> 6;

  const h16* gA = A + (row0 + srow) * (size_t)K + sschunk * 8;
  const h16* gB = W + (col0 + srow) * (size_t)K + sschunk * 8;

  f32x4 acc[MR][4] = {};

  auto stage = [&](int buf, int kt) {
    if (kt >= nt) kt -= nt;
    const int k0 = kt << 6;
#pragma unroll
    for (int i = 0; i < 4; ++i)
      gload16(gA + (size_t)(i * 64) * K + k0, &As[buf][i * 4096 + tid * 8]);
#pragma unroll
    for (int i = 0; i < BN / 64; ++i)
      gload16(gB + (size_t)(i * 64) * K + k0, &Bs[buf][i * 4096 + tid * 8]);
  };

  stage(0, 0);
  for (int t = 0; t < nt; ++t) {
    const int p = t & 1;
    stage(p ^ 1, t + 1);
    waitvN<NLD>();
    __builtin_amdgcn_s_barrier();
    __builtin_amdgcn_sched_barrier(0);
    half8 breg[2][4];
#pragma unroll
    for (int ks = 0; ks < 2; ++ks)
#pragma unroll
      for (int ni = 0; ni < 4; ++ni) {
        const int r = wn * 64 + ni * 16 + l15;
        const int ch = (ks * 4 + kq) ^ (l15 & 7);
        breg[ks][ni] = *(const half8*)&Bs[p][r * 64 + ch * 8];
      }
#pragma unroll
    for (int mi = 0; mi < MR; ++mi) {
      const int r = wm * (MR * 16) + mi * 16 + l15;
      const int ch0 = kq ^ (l15 & 7);
      const int ch1 = (4 + kq) ^ (l15 & 7);
      half8 a0 = *(const half8*)&As[p][r * 64 + ch0 * 8];
      half8 a1 = *(const half8*)&As[p][r * 64 + ch1 * 8];
#pragma unroll
      for (int ni = 0; ni < 4; ++ni)
        acc[mi][ni] = __builtin_amdgcn_mfma_f32_16x16x32_f16(a0, breg[0][ni], acc[mi][ni], 0, 0, 0);
#pragma unroll
      for (int ni = 0; ni < 4; ++ni)
        acc[mi][ni] = __builtin_amdgcn_mfma_f32_16x16x32_f16(a1, breg[1][ni], acc[mi][ni], 0, 0, 0);
    }
    __builtin_amdgcn_sched_barrier(0);
    __builtin_amdgcn_s_barrier();
    __builtin_amdgcn_sched_barrier(0);
  }

#pragma unroll
  for (int mi = 0; mi < MR; ++mi)
#pragma unroll
    for (int ni = 0; ni < 4; ++ni) {
      const size_t col = col0 + wn * 64 + ni * 16 + l15;
      const float bv = bias[col];
#pragma unroll
      for (int ri = 0; ri < 4; ++ri) {
        const size_t row = row0 + wm * (MR * 16) + mi * 16 + kq * 4 + ri;
        float v = acc[mi][ni][ri] + bv;
        C[row * N + col] = (h16)fmaxf(v, 0.f);
      }
    }
}

// ---- fused embedding gather + interaction.
__global__ __launch_bounds__(256) void interact_k(
    const h16* __restrict__ X, const float* __restrict__ emb,
    const int* __restrict__ lSi, h16* __restrict__ z) {
  __shared__ __align__(16) h16 T[4][32][136];
  const int lane = threadIdx.x & 63;
  const int wv = threadIdx.x >> 6;
  const size_t b = (size_t)blockIdx.x * 4 + wv;

  for (int i = lane; i < 5 * 128; i += 64)
    T[wv][27 + (i >> 7)][i & 127] = (h16)0.f;

  {
    half2v v = *(const half2v*)(X + b * 128 + lane * 2);
    *(half2v*)&T[wv][0][lane * 2] = v;
    *(half2v*)(z + b * 512 + lane * 2) = v;
  }
  for (int t = 0; t < NTAB; ++t) {
    int idx = lSi[t * NB + (int)b];
    f32x2 v = *(const f32x2*)(emb + ((size_t)t * NR + idx) * 128 + lane * 2);
    half2v h;
    h[0] = (h16)v.x;
    h[1] = (h16)v.y;
    *(half2v*)&T[wv][1 + t][lane * 2] = h;
  }

  __syncthreads();

  f32x4 acc00 = {}, acc10 = {}, acc11 = {};
  const int l15 = lane & 15;
  const int kq = lane >> 4;
#pragma unroll
  for (int kk = 0; kk < 4; ++kk) {
    const int ko = kk * 32 + kq * 8;
    half8 a0 = *(const half8*)&T[wv][l15][ko];
    half8 a1 = *(const half8*)&T[wv][16 + l15][ko];
    acc00 = __builtin_amdgcn_mfma_f32_16x16x32_f16(a0, a0, acc00, 0, 0, 0);
    acc10 = __builtin_amdgcn_mfma_f32_16x16x32_f16(a1, a0, acc10, 0, 0, 0);
    acc11 = __builtin_amdgcn_mfma_f32_16x16x32_f16(a1, a1, acc11, 0, 0, 0);
  }
  h16* zr = z + b * 512 + 128;
#pragma unroll
  for (int ri = 0; ri < 4; ++ri) {
    int i0 = kq * 4 + ri;
    int i1 = 16 + i0;
    if (l15 < i0) zr[i0 * (i0 - 1) / 2 + l15] = (h16)acc00[ri];
    if (i1 < 27) {
      zr[i1 * (i1 - 1) / 2 + l15] = (h16)acc10[ri];
      int j1 = 16 + l15;
      if (j1 < i1) zr[i1 * (i1 - 1) / 2 + j1] = (h16)acc11[ri];
    }
  }
}

// ---- final layer: out[b] = sigmoid(U3[b,:256] . tw4 + tb4), f32 out
__global__ __launch_bounds__(256) void top4_k(
    const h16* __restrict__ U, const float* __restrict__ w,
    const float* __restrict__ bias, float* __restrict__ out) {
  int r = blockIdx.x * 256 + threadIdx.x;
  const h16* ur = U + (size_t)r * 256;
  float acc = 0.f;
#pragma unroll
  for (int k0 = 0; k0 < 256; k0 += 8) {
    half8 v = *(const half8*)&ur[k0];
#pragma unroll
    for (int j = 0; j < 8; ++j) acc += (float)v[j] * w[k0 + j];
  }
  acc += bias[0];
  out[r] = 1.f / (1.f + expf(-acc));
}

extern "C" void kernel_launch(void* const* d_in, const int* in_sizes, int n_in,
                              void* d_out, int out_size, void* d_ws, size_t ws_size,
                              hipStream_t stream) {
  const float* dense_x = (const float*)d_in[0];
  const int* lSi = (const int*)d_in[2];
  const float* emb = (const float*)d_in[3];
  const float* bw0 = (const float*)d_in[4];
  const float* bb0 = (const float*)d_in[5];
  const float* bw1 = (const float*)d_in[6];
  const float* bb1 = (const float*)d_in[7];
  const float* bw2 = (const float*)d_in[8];
  const float* bb2 = (const float*)d_in[9];
  const float* tw0 = (const float*)d_in[10];
  const float* tb0 = (const float*)d_in[11];
  const float* tw1 = (const float*)d_in[12];
  const float* tb1 = (const float*)d_in[13];
  const float* tw2 = (const float*)d_in[14];
  const float* tb2 = (const float*)d_in[15];
  const float* tw3 = (const float*)d_in[16];
  const float* tb3 = (const float*)d_in[17];
  const float* tw4 = (const float*)d_in[18];
  const float* tb4 = (const float*)d_in[19];
  float* out = (float*)d_out;

  char* ws = (char*)d_ws;
  const size_t MB = (size_t)1 << 20;
  h16* Y0 = (h16*)(ws + 0 * MB);    // [B,512]   16MB   (dead after L1)
  h16* Y1 = (h16*)(ws + 16 * MB);   // [B,256]    8MB   (dead after L2)
  h16* Xc = (h16*)(ws + 24 * MB);   // [B,128]    4MB   (dead after interact)
  h16* Zz = (h16*)(ws + 32 * MB);   // [B,512]   16MB   (dead after T0)
  h16* U0 = (h16*)(ws + 48 * MB);   // [B,1024]  32MB   (dead after T1)
  h16* U1 = (h16*)(ws + 0 * MB);    // [B,1024]  32MB   reuses Y0/Y1/Xc
  h16* U2 = (h16*)(ws + 32 * MB);   // [B,512]   16MB   reuses Zz
  h16* U3 = (h16*)(ws + 48 * MB);   // [B,256]    8MB   reuses U0
  h16* w1p = (h16*)(ws + 80 * MB);  // fp16 weights, contiguous segments
  h16* w2p = w1p + 256 * 512;
  h16* t0p = w2p + 128 * 256;
  h16* t1p = t0p + 1024 * 512;
  h16* t2p = t1p + 1024 * 1024;
  h16* t3p = t2p + 512 * 1024;
  (void)in_sizes; (void)n_in; (void)out_size; (void)ws_size;

  cvt_all_k<<<9344, 256, 0, stream>>>(bw1, bw2, tw0, tw1, tw2, tw3, w1p);

  bot0_k<<<NB * 512 / 256, 256, 0, stream>>>(dense_x, bw0, bb0, Y0);
  gemm_hd<<<dim3(NB / 128, 2), 256, 0, stream>>>(Y0, w1p, bb1, Y1, 256, 512);
  gemm_hd<<<dim3(NB / 128, 1), 256, 0, stream>>>(Y1, w2p, bb2, Xc, 128, 256);
  interact_k<<<NB / 4, 256, 0, stream>>>(Xc, emb, lSi, Zz);
  gemm256<256><<<dim3(NB / 256, 4), 512, 0, stream>>>(Zz, t0p, tb0, U0, 1024, 512);
  gemm256<256><<<dim3(NB / 256, 4), 512, 0, stream>>>(U0, t1p, tb1, U1, 1024, 1024);
  gemm256<128><<<dim3(NB / 256, 4), 512, 0, stream>>>(U1, t2p, tb2, U2, 512, 1024);
  gemm_hd<<<dim3(NB / 128, 2), 256, 0, stream>>>(U2, t3p, tb3, U3, 256, 512);
  top4_k<<<NB / 256, 256, 0, stream>>>(U3, tw4, tb4, out);
}

// Round 5
// 216.215 us; speedup vs baseline: 1.0656x; 1.0306x over previous
//
#include <hip/hip_runtime.h>
#include <cstdint>
#include <cstddef>

typedef _Float16 h16;
typedef __attribute__((ext_vector_type(8))) _Float16 half8;
typedef __attribute__((ext_vector_type(2))) _Float16 half2v;
typedef __attribute__((ext_vector_type(4))) float f32x4;
typedef __attribute__((ext_vector_type(2))) float f32x2;

#define NB 16384
#define NTAB 26
#define NR 100000

__device__ __forceinline__ void gload16(const void* g, void* l) {
  __builtin_amdgcn_global_load_lds(
      (const __attribute__((address_space(1))) unsigned int*)g,
      (__attribute__((address_space(3))) unsigned int*)l, 16, 0, 0);
}

// ---- bottom layer 0: Y[B,512] = relu(x[B,13] @ W0[512,13]^T + b0), fp16 out
__global__ __launch_bounds__(256) void bot0_k(
    const float* __restrict__ x, const float* __restrict__ W,
    const float* __restrict__ bias, h16* __restrict__ Y) {
  int gid = blockIdx.x * 256 + threadIdx.x;
  int row = gid >> 9;
  int n = gid & 511;
  const float* xr = x + row * 13;
  const float* wr = W + n * 13;
  float acc = bias[n];
#pragma unroll
  for (int k = 0; k < 13; ++k) acc += xr[k] * wr[k];
  Y[gid] = (h16)fmaxf(acc, 0.f);
}

// ---- fused f32 -> fp16 weight conversion (all 6 weights, one launch)
__global__ __launch_bounds__(256) void cvt_all_k(
    const float* __restrict__ s0, const float* __restrict__ s1,
    const float* __restrict__ s2, const float* __restrict__ s3,
    const float* __restrict__ s4, const float* __restrict__ s5,
    h16* __restrict__ dst) {
  int b = blockIdx.x;
  const float* src; int K, kl, i0; size_t doff;
  if (b < 512)       { src=s0; K=512;  kl=9;  i0=(b-0)*256;    doff=0; }
  else if (b < 640)  { src=s1; K=256;  kl=8;  i0=(b-512)*256;  doff=131072; }
  else if (b < 2688) { src=s2; K=479;  kl=9;  i0=(b-640)*256;  doff=163840; }
  else if (b < 6784) { src=s3; K=1024; kl=10; i0=(b-2688)*256; doff=688128; }
  else if (b < 8832) { src=s4; K=1024; kl=10; i0=(b-6784)*256; doff=1736704; }
  else               { src=s5; K=512;  kl=9;  i0=(b-8832)*256; doff=2260992; }
  int i = i0 + threadIdx.x;
  int n = i >> kl, k = i & ((1 << kl) - 1);
  dst[doff + i] = (k < K) ? (h16)src[(size_t)n * K + k] : (h16)0.f;
}

// ---- 128x128-tile double-buffered counted-vmcnt fp16 MFMA GEMM.
// C[M,N] = relu(A[M,K] @ W[N,K]^T + bias). 4 waves (2x2 of 64x64), BK=64,
// 64KB LDS -> 2 blocks/CU (cross-block overlap hides barrier drains).
// Loop never drains vmcnt (wait vmcnt(8) leaves next tile's loads in
// flight); wrap-prefetch keeps counts uniform. 1-D grid with XCD-aware
// decode: blocks sharing an A-row-tile land on the same XCD (same b%8),
// so A re-reads across col-tiles hit that XCD's L2.
// GYL = log2(N/128). Grid = 128 * (N/128) blocks (M = 16384 fixed).
template <int GYL>
__global__ __launch_bounds__(256, 2) void gemm_hd(
    const h16* __restrict__ A, const h16* __restrict__ W,
    const float* __restrict__ bias, h16* __restrict__ C, int N, int K) {
  __shared__ __align__(16) h16 As[2][128 * 64];
  __shared__ __align__(16) h16 Bs[2][128 * 64];
  const int b = blockIdx.x;
  const int c8 = b & 7;
  const int q = b >> 3;
  const int jcol = q & ((1 << GYL) - 1);
  const int krow = ((q >> GYL) << 3) | c8;
  const int tid = threadIdx.x;
  const int lane = tid & 63;
  const int wave = tid >> 6;
  const int wm = wave >> 1, wn = wave & 1;
  const size_t row0 = (size_t)krow * 128;
  const size_t col0 = (size_t)jcol * 128;
  const int lr = lane >> 3;
  const int swzc = (((lane & 7) ^ lr) << 3);
  const int l15 = lane & 15;
  const int kq = lane >> 4;
  const int l7 = lane & 7;
  const int nt = K >> 6;

  const h16* ga = A + (row0 + wave * 32 + lr) * (size_t)K + swzc;
  const h16* gb = W + (col0 + wave * 32 + lr) * (size_t)K + swzc;

  f32x4 acc[4][4] = {};

  auto stage = [&](int buf, int kt) {
    if (kt >= nt) kt -= nt;
    const int k0 = kt << 6;
    h16* la = As[buf] + wave * 2048;
    h16* lb = Bs[buf] + wave * 2048;
#pragma unroll
    for (int i = 0; i < 4; ++i) {
      gload16(ga + (size_t)i * 8 * K + k0, la + i * 512);
      gload16(gb + (size_t)i * 8 * K + k0, lb + i * 512);
    }
  };

  stage(0, 0);
  for (int t = 0; t < nt; ++t) {
    const int p = t & 1;
    stage(p ^ 1, t + 1);
    asm volatile("s_waitcnt vmcnt(8)" ::: "memory");
    __builtin_amdgcn_s_barrier();
    __builtin_amdgcn_sched_barrier(0);
#pragma unroll
    for (int kk = 0; kk < 2; ++kk) {
      half8 a[4], bfr[4];
      const int kb = kk * 4 + kq;
#pragma unroll
      for (int mi = 0; mi < 4; ++mi)
        a[mi] = *(const half8*)&As[p][(wm * 64 + mi * 16 + l15) * 64 + ((kb ^ l7) << 3)];
#pragma unroll
      for (int ni = 0; ni < 4; ++ni)
        bfr[ni] = *(const half8*)&Bs[p][(wn * 64 + ni * 16 + l15) * 64 + ((kb ^ l7) << 3)];
#pragma unroll
      for (int mi = 0; mi < 4; ++mi)
#pragma unroll
        for (int ni = 0; ni < 4; ++ni)
          acc[mi][ni] = __builtin_amdgcn_mfma_f32_16x16x32_f16(a[mi], bfr[ni], acc[mi][ni], 0, 0, 0);
    }
    __builtin_amdgcn_sched_barrier(0);
    __builtin_amdgcn_s_barrier();
    __builtin_amdgcn_sched_barrier(0);
  }

#pragma unroll
  for (int mi = 0; mi < 4; ++mi)
#pragma unroll
    for (int ni = 0; ni < 4; ++ni) {
      const size_t col = col0 + wn * 64 + ni * 16 + l15;
      const float bv = bias[col];
#pragma unroll
      for (int ri = 0; ri < 4; ++ri) {
        const size_t row = row0 + wm * 64 + mi * 16 + kq * 4 + ri;
        float v = acc[mi][ni][ri] + bv;
        C[row * N + col] = (h16)fmaxf(v, 0.f);
      }
    }
}

// ---- fused embedding gather + interaction.
__global__ __launch_bounds__(256) void interact_k(
    const h16* __restrict__ X, const float* __restrict__ emb,
    const int* __restrict__ lSi, h16* __restrict__ z) {
  __shared__ __align__(16) h16 T[4][32][136];
  const int lane = threadIdx.x & 63;
  const int wv = threadIdx.x >> 6;
  const size_t b = (size_t)blockIdx.x * 4 + wv;

  for (int i = lane; i < 5 * 128; i += 64)
    T[wv][27 + (i >> 7)][i & 127] = (h16)0.f;

  {
    half2v v = *(const half2v*)(X + b * 128 + lane * 2);
    *(half2v*)&T[wv][0][lane * 2] = v;
    *(half2v*)(z + b * 512 + lane * 2) = v;
  }
  for (int t = 0; t < NTAB; ++t) {
    int idx = lSi[t * NB + (int)b];
    f32x2 v = *(const f32x2*)(emb + ((size_t)t * NR + idx) * 128 + lane * 2);
    half2v h;
    h[0] = (h16)v.x;
    h[1] = (h16)v.y;
    *(half2v*)&T[wv][1 + t][lane * 2] = h;
  }

  __syncthreads();

  f32x4 acc00 = {}, acc10 = {}, acc11 = {};
  const int l15 = lane & 15;
  const int kq = lane >> 4;
#pragma unroll
  for (int kk = 0; kk < 4; ++kk) {
    const int ko = kk * 32 + kq * 8;
    half8 a0 = *(const half8*)&T[wv][l15][ko];
    half8 a1 = *(const half8*)&T[wv][16 + l15][ko];
    acc00 = __builtin_amdgcn_mfma_f32_16x16x32_f16(a0, a0, acc00, 0, 0, 0);
    acc10 = __builtin_amdgcn_mfma_f32_16x16x32_f16(a1, a0, acc10, 0, 0, 0);
    acc11 = __builtin_amdgcn_mfma_f32_16x16x32_f16(a1, a1, acc11, 0, 0, 0);
  }
  h16* zr = z + b * 512 + 128;
#pragma unroll
  for (int ri = 0; ri < 4; ++ri) {
    int i0 = kq * 4 + ri;
    int i1 = 16 + i0;
    if (l15 < i0) zr[i0 * (i0 - 1) / 2 + l15] = (h16)acc00[ri];
    if (i1 < 27) {
      zr[i1 * (i1 - 1) / 2 + l15] = (h16)acc10[ri];
      int j1 = 16 + l15;
      if (j1 < i1) zr[i1 * (i1 - 1) / 2 + j1] = (h16)acc11[ri];
    }
  }
}

// ---- final layer: out[b] = sigmoid(U3[b,:256] . tw4 + tb4), f32 out
__global__ __launch_bounds__(256) void top4_k(
    const h16* __restrict__ U, const float* __restrict__ w,
    const float* __restrict__ bias, float* __restrict__ out) {
  int r = blockIdx.x * 256 + threadIdx.x;
  const h16* ur = U + (size_t)r * 256;
  float acc = 0.f;
#pragma unroll
  for (int k0 = 0; k0 < 256; k0 += 8) {
    half8 v = *(const half8*)&ur[k0];
#pragma unroll
    for (int j = 0; j < 8; ++j) acc += (float)v[j] * w[k0 + j];
  }
  acc += bias[0];
  out[r] = 1.f / (1.f + expf(-acc));
}

extern "C" void kernel_launch(void* const* d_in, const int* in_sizes, int n_in,
                              void* d_out, int out_size, void* d_ws, size_t ws_size,
                              hipStream_t stream) {
  const float* dense_x = (const float*)d_in[0];
  const int* lSi = (const int*)d_in[2];
  const float* emb = (const float*)d_in[3];
  const float* bw0 = (const float*)d_in[4];
  const float* bb0 = (const float*)d_in[5];
  const float* bw1 = (const float*)d_in[6];
  const float* bb1 = (const float*)d_in[7];
  const float* bw2 = (const float*)d_in[8];
  const float* bb2 = (const float*)d_in[9];
  const float* tw0 = (const float*)d_in[10];
  const float* tb0 = (const float*)d_in[11];
  const float* tw1 = (const float*)d_in[12];
  const float* tb1 = (const float*)d_in[13];
  const float* tw2 = (const float*)d_in[14];
  const float* tb2 = (const float*)d_in[15];
  const float* tw3 = (const float*)d_in[16];
  const float* tb3 = (const float*)d_in[17];
  const float* tw4 = (const float*)d_in[18];
  const float* tb4 = (const float*)d_in[19];
  float* out = (float*)d_out;

  char* ws = (char*)d_ws;
  const size_t MB = (size_t)1 << 20;
  h16* Y0 = (h16*)(ws + 0 * MB);    // [B,512]   16MB   (dead after L1)
  h16* Y1 = (h16*)(ws + 16 * MB);   // [B,256]    8MB   (dead after L2)
  h16* Xc = (h16*)(ws + 24 * MB);   // [B,128]    4MB   (dead after interact)
  h16* Zz = (h16*)(ws + 32 * MB);   // [B,512]   16MB   (dead after T0)
  h16* U0 = (h16*)(ws + 48 * MB);   // [B,1024]  32MB   (dead after T1)
  h16* U1 = (h16*)(ws + 0 * MB);    // [B,1024]  32MB   reuses Y0/Y1/Xc
  h16* U2 = (h16*)(ws + 32 * MB);   // [B,512]   16MB   reuses Zz
  h16* U3 = (h16*)(ws + 48 * MB);   // [B,256]    8MB   reuses U0
  h16* w1p = (h16*)(ws + 80 * MB);  // fp16 weights, contiguous segments
  h16* w2p = w1p + 256 * 512;
  h16* t0p = w2p + 128 * 256;
  h16* t1p = t0p + 1024 * 512;
  h16* t2p = t1p + 1024 * 1024;
  h16* t3p = t2p + 512 * 1024;
  (void)in_sizes; (void)n_in; (void)out_size; (void)ws_size;

  cvt_all_k<<<9344, 256, 0, stream>>>(bw1, bw2, tw0, tw1, tw2, tw3, w1p);

  bot0_k<<<NB * 512 / 256, 256, 0, stream>>>(dense_x, bw0, bb0, Y0);
  gemm_hd<1><<<128 * 2, 256, 0, stream>>>(Y0, w1p, bb1, Y1, 256, 512);
  gemm_hd<0><<<128 * 1, 256, 0, stream>>>(Y1, w2p, bb2, Xc, 128, 256);
  interact_k<<<NB / 4, 256, 0, stream>>>(Xc, emb, lSi, Zz);
  gemm_hd<3><<<128 * 8, 256, 0, stream>>>(Zz, t0p, tb0, U0, 1024, 512);
  gemm_hd<3><<<128 * 8, 256, 0, stream>>>(U0, t1p, tb1, U1, 1024, 1024);
  gemm_hd<2><<<128 * 4, 256, 0, stream>>>(U1, t2p, tb2, U2, 512, 1024);
  gemm_hd<1><<<128 * 2, 256, 0, stream>>>(U2, t3p, tb3, U3, 256, 512);
  top4_k<<<NB / 256, 256, 0, stream>>>(U3, tw4, tb4, out);
}